// Round 5
// baseline (499.175 us; speedup 1.0000x reference)
//
#include <hip/hip_runtime.h>
#include <hip/hip_bf16.h>
#include <stdint.h>

#define SQ 2048
#define DK 64
#define NB 32
#define TQ 16
#define EW 2064            // fp16 elems per LDS score row
#define NTHREADS 512
#define SCL 0.18033688011112042f   // log2(e)/8

typedef __attribute__((ext_vector_type(8))) short short8;
typedef __attribute__((ext_vector_type(4))) float f32x4;
typedef __attribute__((ext_vector_type(4))) unsigned u32x4;
typedef __attribute__((ext_vector_type(2))) unsigned u32x2;

// ---- bf16 helpers (RNE) ----
__device__ __forceinline__ unsigned f2bf_u(float x) {
    unsigned u = __builtin_bit_cast(unsigned, x);
    u += 0x7fffu + ((u >> 16) & 1u);
    return u >> 16;
}
__device__ __forceinline__ float bf2f(unsigned h) {
    return __builtin_bit_cast(float, h << 16);
}
__device__ __forceinline__ void split8(const float* p, short8& h, short8& l) {
    f32x4 a = *(const f32x4*)p;
    f32x4 b = *(const f32x4*)(p + 4);
    #pragma unroll
    for (int j = 0; j < 4; ++j) {
        unsigned ua = f2bf_u(a[j]);
        h[j] = (short)ua; l[j] = (short)f2bf_u(a[j] - bf2f(ua));
        unsigned ub = f2bf_u(b[j]);
        h[j + 4] = (short)ub; l[j + 4] = (short)f2bf_u(b[j] - bf2f(ub));
    }
}
__device__ __forceinline__ unsigned pkf16(float a, float b) {
    unsigned short ha = __builtin_bit_cast(unsigned short, (_Float16)a);
    unsigned short hb = __builtin_bit_cast(unsigned short, (_Float16)b);
    return (unsigned)ha | ((unsigned)hb << 16);
}
__device__ __forceinline__ float upk16(unsigned u, int hi) {
    return (float)__builtin_bit_cast(_Float16, (unsigned short)(hi ? (u >> 16) : (u & 0xffffu)));
}

// ============ prep: K -> bf16 hi/lo planes; V -> transposed bf16 plane ============
__global__ __launch_bounds__(256) void prep_kernel(
    const float* __restrict__ K, const float* __restrict__ V,
    unsigned short* __restrict__ Khi, unsigned short* __restrict__ Klo,
    unsigned short* __restrict__ Vt)
{
    __shared__ float vtile[64][65];
    const int t  = threadIdx.x;
    const int b  = blockIdx.x >> 5;
    const int s0 = (blockIdx.x & 31) << 6;
    const size_t base = ((size_t)b * SQ + s0) * DK + (size_t)t * 16;

    {
        short8 h0, l0, h1, l1;
        split8(K + base,     h0, l0);
        split8(K + base + 8, h1, l1);
        *(short8*)(Khi + base)     = h0;
        *(short8*)(Khi + base + 8) = h1;
        *(short8*)(Klo + base)     = l0;
        *(short8*)(Klo + base + 8) = l1;
    }
    {
        const int sr = t >> 2, dc = (t & 3) << 4;
        #pragma unroll
        for (int u = 0; u < 16; u += 4) {
            f32x4 v = *(const f32x4*)(V + base + u);
            vtile[sr][dc + u + 0] = v[0];
            vtile[sr][dc + u + 1] = v[1];
            vtile[sr][dc + u + 2] = v[2];
            vtile[sr][dc + u + 3] = v[3];
        }
    }
    __syncthreads();
    #pragma unroll
    for (int rep = 0; rep < 16; ++rep) {
        const int idx = rep * 256 + t;
        const int d = idx >> 6, s = idx & 63;
        Vt[((size_t)b * DK + d) * SQ + s0 + s] = (unsigned short)f2bf_u(vtile[s][d]);
    }
}

// ============ main fused kernel ============
__global__ __launch_bounds__(NTHREADS, 4) void sdpa_main(
    const float* __restrict__ Q, const unsigned short* __restrict__ Khi,
    const unsigned short* __restrict__ Klo, const unsigned short* __restrict__ Vt,
    const unsigned* __restrict__ Mk, float* __restrict__ Yout, float* __restrict__ Aout)
{
    __shared__ __align__(16) unsigned short e_lds[TQ][EW];  // 66048 B
    __shared__ float yp[4][TQ][16];                         // 4 KB
    __shared__ float rsum[8][TQ];
    __shared__ float i2s[TQ];

    const int tid  = threadIdx.x;
    const int lane = tid & 63;
    const int wv   = tid >> 6;
    const int m16  = lane & 15;
    const int kq   = lane >> 4;
    const int koff = kq * 8;

    const int b  = blockIdx.x >> 7;
    const int q0 = (blockIdx.x & 127) * TQ;

    // C-phase mapping (needed early for top-of-kernel mask prefetch)
    const int cr = tid >> 5;            // C row (0..15)
    const int cc = (tid & 31) * 8;      // C col base within stripe
    const int xc = (cr & 7) << 3;
    const size_t crow = ((size_t)b * SQ + q0 + cr) * SQ + cc;

    // ---- deep prefetch: mask stripes 0 and 1 fly during phase A ----
    u32x4 ma0 = __builtin_nontemporal_load((const u32x4*)(Mk + crow));
    u32x4 mb0 = __builtin_nontemporal_load((const u32x4*)(Mk + crow + 4));
    u32x4 ma1 = __builtin_nontemporal_load((const u32x4*)(Mk + crow + 256));
    u32x4 mb1 = __builtin_nontemporal_load((const u32x4*)(Mk + crow + 256 + 4));

    // Q fragments (B-operand), split bf16
    short8 qh[2], ql[2];
    {
        const float* qrow = Q + ((size_t)b * SQ + q0 + m16) * DK;
        split8(qrow + koff,      qh[0], ql[0]);
        split8(qrow + 32 + koff, qh[1], ql[1]);
    }

    // ---- Phase A: e = exp(QK^T/8) (fp16, swizzled LDS); row sums in-register ----
    float rs = 0.f;
    {
        const size_t krow = ((size_t)b * SQ + wv * 256 + m16) * DK;
        const unsigned short* khp = Khi + krow;
        const unsigned short* klp = Klo + krow;
        const int xw = (m16 & 7) << 3;
        for (int t = 0; t < 16; ++t) {
            const int off = t * 16 * DK;
            f32x4 acc = {0.f, 0.f, 0.f, 0.f};
            #pragma unroll
            for (int c = 0; c < 2; ++c) {
                short8 kh = *(const short8*)(khp + off + c * 32 + koff);
                short8 kl = *(const short8*)(klp + off + c * 32 + koff);
                acc = __builtin_amdgcn_mfma_f32_16x16x32_bf16(kh, qh[c], acc, 0, 0, 0);
                acc = __builtin_amdgcn_mfma_f32_16x16x32_bf16(kh, ql[c], acc, 0, 0, 0);
                acc = __builtin_amdgcn_mfma_f32_16x16x32_bf16(kl, qh[c], acc, 0, 0, 0);
            }
            const float e0 = exp2f(acc[0] * SCL);
            const float e1 = exp2f(acc[1] * SCL);
            const float e2 = exp2f(acc[2] * SCL);
            const float e3 = exp2f(acc[3] * SCL);
            rs += (e0 + e1) + (e2 + e3);
            u32x2 pk;
            pk[0] = pkf16(e0, e1);
            pk[1] = pkf16(e2, e3);
            *(u32x2*)&e_lds[m16][(wv * 256 + t * 16 + kq * 4) ^ xw] = pk;
        }
    }
    rs += __shfl_xor(rs, 16);
    rs += __shfl_xor(rs, 32);
    if (lane < 16) rsum[wv][lane] = rs;
    __syncthreads();
    if (tid < 16) {
        float s = 0.f;
        #pragma unroll
        for (int w = 0; w < 8; ++w) s += rsum[w][tid];
        i2s[tid] = 2.0f / s;       // includes dropout keep-scale
    }
    __syncthreads();

    // ---- merged CD phase: stream mask+attn while PV MFMAs run underneath ----
    const float i2 = i2s[cr];

    const int g   = wv >> 1;            // d-group 0..3
    const int par = wv & 1;             // k-parity
    const int xm  = (m16 & 7) << 3;
    const unsigned short* vrow = Vt + ((size_t)b * DK + g * 16 + m16) * SQ;
    f32x4 acc = {0.f, 0.f, 0.f, 0.f};

    #define C_FINISH(s, ma, mb)                                                   \
    {                                                                             \
        unsigned short* ep = &e_lds[cr][((s) * 256 + cc) ^ xc];                   \
        const u32x4 ev = *(const u32x4*)ep;                                       \
        const float a0 = (ma)[0] ? upk16(ev[0], 0) * i2 : 0.f;                    \
        const float a1 = (ma)[1] ? upk16(ev[0], 1) * i2 : 0.f;                    \
        const float a2 = (ma)[2] ? upk16(ev[1], 0) * i2 : 0.f;                    \
        const float a3 = (ma)[3] ? upk16(ev[1], 1) * i2 : 0.f;                    \
        const float a4 = (mb)[0] ? upk16(ev[2], 0) * i2 : 0.f;                    \
        const float a5 = (mb)[1] ? upk16(ev[2], 1) * i2 : 0.f;                    \
        const float a6 = (mb)[2] ? upk16(ev[3], 0) * i2 : 0.f;                    \
        const float a7 = (mb)[3] ? upk16(ev[3], 1) * i2 : 0.f;                    \
        f32x4 av0 = {a0, a1, a2, a3};                                             \
        f32x4 av1 = {a4, a5, a6, a7};                                             \
        __builtin_nontemporal_store(av0, (f32x4*)(Aout + crow + (s) * 256));      \
        __builtin_nontemporal_store(av1, (f32x4*)(Aout + crow + (s) * 256 + 4));  \
        u32x4 pb;                                                                 \
        pb[0] = f2bf_u(a0) | (f2bf_u(a1) << 16);                                  \
        pb[1] = f2bf_u(a2) | (f2bf_u(a3) << 16);                                  \
        pb[2] = f2bf_u(a4) | (f2bf_u(a5) << 16);                                  \
        pb[3] = f2bf_u(a6) | (f2bf_u(a7) << 16);                                  \
        *(u32x4*)ep = pb;                                                         \
    }

    // PV on stripe s (reads repacked bf16; disjoint from this step's LDS writes)
    #define PV_STRIPE(s)                                                          \
    {                                                                             \
        _Pragma("unroll")                                                         \
        for (int c = 0; c < 4; ++c) {                                             \
            const int k0 = (s) * 256 + par * 128 + c * 32;                        \
            short8 af = *(const short8*)&e_lds[m16][(k0 + koff) ^ xm];            \
            short8 vf = *(const short8*)(vrow + k0 + koff);                       \
            acc = __builtin_amdgcn_mfma_f32_16x16x32_bf16(af, vf, acc, 0, 0, 0);  \
        }                                                                         \
    }

    // counted barrier: LDS visibility only — global loads/stores stay in flight
    #define CBAR()                                                                \
        asm volatile("s_waitcnt lgkmcnt(0)" ::: "memory");                        \
        __builtin_amdgcn_s_barrier();                                             \
        __builtin_amdgcn_sched_barrier(0);

    #define REFILL(slotA, slotB, s)                                               \
        slotA = __builtin_nontemporal_load((const u32x4*)(Mk + crow + (s) * 256));\
        slotB = __builtin_nontemporal_load((const u32x4*)(Mk + crow + (s) * 256 + 4));

    // stripe 0 ready in LDS before the loop
    C_FINISH(0, ma0, mb0);
    CBAR();

    // even s: refill slot0 <- s+2, consume slot1 (stripe s+1)
    // odd  s: refill slot1 <- s+3? no: <- s+2, consume slot0
    REFILL(ma0, mb0, 2); PV_STRIPE(0); C_FINISH(1, ma1, mb1); CBAR();
    REFILL(ma1, mb1, 3); PV_STRIPE(1); C_FINISH(2, ma0, mb0); CBAR();
    REFILL(ma0, mb0, 4); PV_STRIPE(2); C_FINISH(3, ma1, mb1); CBAR();
    REFILL(ma1, mb1, 5); PV_STRIPE(3); C_FINISH(4, ma0, mb0); CBAR();
    REFILL(ma0, mb0, 6); PV_STRIPE(4); C_FINISH(5, ma1, mb1); CBAR();
    REFILL(ma1, mb1, 7); PV_STRIPE(5); C_FINISH(6, ma0, mb0); CBAR();
                         PV_STRIPE(6); C_FINISH(7, ma1, mb1); CBAR();
                         PV_STRIPE(7);

    #undef REFILL
    #undef CBAR
    #undef PV_STRIPE
    #undef C_FINISH

    // ---- combine k-parities, write y ----
    if (par == 1) {
        #pragma unroll
        for (int r = 0; r < 4; ++r) yp[g][kq * 4 + r][m16] = acc[r];
    }
    __syncthreads();
    if (par == 0) {
        #pragma unroll
        for (int r = 0; r < 4; ++r) {
            const float yv = acc[r] + yp[g][kq * 4 + r][m16];
            __builtin_nontemporal_store(yv,
                Yout + ((size_t)b * SQ + q0 + kq * 4 + r) * DK + g * 16 + m16);
        }
    }
}

extern "C" void kernel_launch(void* const* d_in, const int* in_sizes, int n_in,
                              void* d_out, int out_size, void* d_ws, size_t ws_size,
                              hipStream_t stream) {
    const float*    Q  = (const float*)d_in[0];
    const float*    K  = (const float*)d_in[1];
    const float*    V  = (const float*)d_in[2];
    const unsigned* Mk = (const unsigned*)d_in[3];
    float* Yout = (float*)d_out;
    float* Aout = (float*)d_out + (size_t)NB * SQ * DK;

    const size_t NEL = (size_t)NB * SQ * DK;
    unsigned short* Khi = (unsigned short*)d_ws;
    unsigned short* Klo = Khi + NEL;
    unsigned short* Vt  = Klo + NEL;

    prep_kernel<<<dim3(NB * (SQ / 64)), dim3(256), 0, stream>>>(K, V, Khi, Klo, Vt);
    sdpa_main<<<dim3(NB * (SQ / TQ)), dim3(NTHREADS), 0, stream>>>(
        Q, Khi, Klo, Vt, Mk, Yout, Aout);
}